// Round 2
// baseline (256.809 us; speedup 1.0000x reference)
//
#include <hip/hip_runtime.h>
#include <hip/hip_bf16.h>

#define BATCH 64
#define SEQT  512
#define EMB   1024
#define HID   2048
#define VOC   32000

using bf16x8 = __attribute__((ext_vector_type(8))) __bf16;
using f32x4  = __attribute__((ext_vector_type(4))) float;

__device__ __forceinline__ void split2(float x, __bf16& hi, __bf16& lo) {
  hi = (__bf16)x;
  lo = (__bf16)(x - (float)hi);
}

// ---------------------------------------------------------------------------
// Layer kernel: h_out = tanh(A @ W + bias), all math in split-bf16 (hi+lo
// planes, 3 MFMA products = ~16-bit-mantissa precision; f32 accumulate).
// GATHER=true: A row m = emb[X[m*SEQT+SEQT-1]] (f32, split on the fly).
// Grid: 128 blocks (one 16-col N-tile), 512 thr = 8 waves; each wave owns
// KTOT/8 of K; partials reduced via LDS; epilogue = bias+tanh+split-store.
// ---------------------------------------------------------------------------
template <int KTOT, bool GATHER>
__global__ __launch_bounds__(512) void layer_kernel(
    const int* __restrict__ X, const float* __restrict__ emb,
    const __hip_bfloat16* __restrict__ hin_hi,
    const __hip_bfloat16* __restrict__ hin_lo,
    const float* __restrict__ W, const float* __restrict__ bias,
    __hip_bfloat16* __restrict__ hout_hi,
    __hip_bfloat16* __restrict__ hout_lo) {
  constexpr int KCHUNK = KTOT / 8;
  constexpr int KSTEPS = KCHUNK / 32;
  __shared__ float red[8 * 16 * 72];  // [wave][n][m padded 64->72]

  const int tid = threadIdx.x;
  const int w = tid >> 6;
  const int l = tid & 63;
  const int ln = l & 15;
  const int lg = l >> 4;
  const int n0 = blockIdx.x * 16;

  f32x4 acc[4];
#pragma unroll
  for (int mt = 0; mt < 4; ++mt) acc[mt] = f32x4{0.f, 0.f, 0.f, 0.f};

  const float* grow[4];
#pragma unroll
  for (int mt = 0; mt < 4; ++mt) {
    if constexpr (GATHER) {
      const int m = ln + 16 * mt;
      const int tok = X[m * SEQT + (SEQT - 1)];
      grow[mt] = emb + (size_t)tok * EMB;
    } else {
      grow[mt] = nullptr;
    }
  }

  const int kwave = w * KCHUNK + lg * 8;
  const float* Wc = W + n0 + ln;

#pragma unroll
  for (int ks = 0; ks < KSTEPS; ++ks) {
    const int kb = kwave + ks * 32;
    float bv[8];
#pragma unroll
    for (int i = 0; i < 8; ++i) bv[i] = Wc[(size_t)(kb + i) * HID];
    bf16x8 bhi, blo;
#pragma unroll
    for (int i = 0; i < 8; ++i) {
      __bf16 h_, l_;
      split2(bv[i], h_, l_);
      bhi[i] = h_;
      blo[i] = l_;
    }

#pragma unroll
    for (int mt = 0; mt < 4; ++mt) {
      bf16x8 ahi, alo;
      if constexpr (GATHER) {
#pragma unroll
        for (int i = 0; i < 8; ++i) {
          __bf16 h_, l_;
          split2(grow[mt][kb + i], h_, l_);
          ahi[i] = h_;
          alo[i] = l_;
        }
      } else {
        const size_t off = (size_t)(ln + 16 * mt) * KTOT + kb;
        ahi = *reinterpret_cast<const bf16x8*>(hin_hi + off);
        alo = *reinterpret_cast<const bf16x8*>(hin_lo + off);
      }
      acc[mt] = __builtin_amdgcn_mfma_f32_16x16x32_bf16(ahi, bhi, acc[mt], 0, 0, 0);
      acc[mt] = __builtin_amdgcn_mfma_f32_16x16x32_bf16(alo, bhi, acc[mt], 0, 0, 0);
      acc[mt] = __builtin_amdgcn_mfma_f32_16x16x32_bf16(ahi, blo, acc[mt], 0, 0, 0);
    }
  }

  // stash partials: red[(w*16 + n)*72 + m]; acc[mt][j] -> m = mt*16 + lg*4 + j
  float* dst = &red[(w * 16 + ln) * 72 + lg * 4];
#pragma unroll
  for (int mt = 0; mt < 4; ++mt)
    *reinterpret_cast<f32x4*>(dst + mt * 16) = acc[mt];

  __syncthreads();

#pragma unroll
  for (int r = 0; r < 2; ++r) {
    const int o = tid + r * 512;
    const int m = o >> 4, n = o & 15;
    float s = 0.f;
#pragma unroll
    for (int ww = 0; ww < 8; ++ww) s += red[(ww * 16 + n) * 72 + m];
    s += bias[n0 + n];
    const float hval = tanhf(s);
    __bf16 h_, l_;
    split2(hval, h_, l_);
    const size_t off = (size_t)m * HID + (n0 + n);
    hout_hi[off] = *reinterpret_cast<__hip_bfloat16*>(&h_);
    hout_lo[off] = *reinterpret_cast<__hip_bfloat16*>(&l_);
  }
}

// ---------------------------------------------------------------------------
// Output kernel: out[64][VOC] = h @ W_hy + b_y, split-bf16 (3 products).
// Grid: 500 blocks x 256 thr (4 waves); wave owns a 64x16 tile, full K=2048.
// W_hy streamed f32 nontemporal (262 MB dominates total runtime).
// ---------------------------------------------------------------------------
__global__ __launch_bounds__(256) void out_kernel(
    const __hip_bfloat16* __restrict__ h_hi,
    const __hip_bfloat16* __restrict__ h_lo, const float* __restrict__ Why,
    const float* __restrict__ by, float* __restrict__ out) {
  const int tid = threadIdx.x;
  const int w = tid >> 6;
  const int l = tid & 63;
  const int ln = l & 15;
  const int lg = l >> 4;
  const int n0 = blockIdx.x * 64 + w * 16;
  const int col = n0 + ln;

  f32x4 acc[4];
#pragma unroll
  for (int mt = 0; mt < 4; ++mt) acc[mt] = f32x4{0.f, 0.f, 0.f, 0.f};

  const float* Wc = Why + col;

#pragma unroll 2
  for (int ks = 0; ks < 64; ++ks) {
    const int kb = ks * 32 + lg * 8;
    float bv[8];
#pragma unroll
    for (int i = 0; i < 8; ++i)
      bv[i] = __builtin_nontemporal_load(Wc + (size_t)(kb + i) * VOC);
    bf16x8 bhi, blo;
#pragma unroll
    for (int i = 0; i < 8; ++i) {
      __bf16 h_, l_;
      split2(bv[i], h_, l_);
      bhi[i] = h_;
      blo[i] = l_;
    }

#pragma unroll
    for (int mt = 0; mt < 4; ++mt) {
      const size_t off = (size_t)(ln + 16 * mt) * HID + kb;
      const bf16x8 ahi = *reinterpret_cast<const bf16x8*>(h_hi + off);
      const bf16x8 alo = *reinterpret_cast<const bf16x8*>(h_lo + off);
      acc[mt] = __builtin_amdgcn_mfma_f32_16x16x32_bf16(ahi, bhi, acc[mt], 0, 0, 0);
      acc[mt] = __builtin_amdgcn_mfma_f32_16x16x32_bf16(alo, bhi, acc[mt], 0, 0, 0);
      acc[mt] = __builtin_amdgcn_mfma_f32_16x16x32_bf16(ahi, blo, acc[mt], 0, 0, 0);
    }
  }

  const float bval = by[col];
#pragma unroll
  for (int mt = 0; mt < 4; ++mt) {
#pragma unroll
    for (int j = 0; j < 4; ++j) {
      const int m = mt * 16 + lg * 4 + j;
      __builtin_nontemporal_store(acc[mt][j] + bval, out + (size_t)m * VOC + col);
    }
  }
}

extern "C" void kernel_launch(void* const* d_in, const int* in_sizes, int n_in,
                              void* d_out, int out_size, void* d_ws,
                              size_t ws_size, hipStream_t stream) {
  const int* X = (const int*)d_in[0];
  const float* emb = (const float*)d_in[1];
  const float* W_xh = (const float*)d_in[2];
  const float* W_hh = (const float*)d_in[3];
  const float* W_hy = (const float*)d_in[4];
  const float* b_h = (const float*)d_in[5];
  const float* b_y = (const float*)d_in[6];
  float* out = (float*)d_out;

  __hip_bfloat16* hA_hi = (__hip_bfloat16*)d_ws;
  __hip_bfloat16* hA_lo = hA_hi + BATCH * HID;
  __hip_bfloat16* hB_hi = hA_lo + BATCH * HID;
  __hip_bfloat16* hB_lo = hB_hi + BATCH * HID;

  dim3 blk(512), grd(128);
  layer_kernel<EMB, true><<<grd, blk, 0, stream>>>(
      X, emb, nullptr, nullptr, W_xh, b_h, hA_hi, hA_lo);
  layer_kernel<HID, false><<<grd, blk, 0, stream>>>(
      nullptr, nullptr, hA_hi, hA_lo, W_hh, b_h, hB_hi, hB_lo);
  layer_kernel<HID, false><<<grd, blk, 0, stream>>>(
      nullptr, nullptr, hB_hi, hB_lo, W_hh, b_h, hA_hi, hA_lo);
  layer_kernel<HID, false><<<grd, blk, 0, stream>>>(
      nullptr, nullptr, hA_hi, hA_lo, W_hh, b_h, hB_hi, hB_lo);
  layer_kernel<HID, false><<<grd, blk, 0, stream>>>(
      nullptr, nullptr, hB_hi, hB_lo, W_hh, b_h, hA_hi, hA_lo);
  out_kernel<<<dim3(500), dim3(256), 0, stream>>>(hA_hi, hA_lo, W_hy, b_y, out);
}